// Round 5
// baseline (766.127 us; speedup 1.0000x reference)
//
#include <hip/hip_runtime.h>
#include <hip/hip_bf16.h>

// ---------------------------------------------------------------------------
// B=2, S=2048, DM=4096, H=32, HKV=8, D=128, causal GQA attention.
//   qkv = X@[Wq;Wk;Wv]^T (ONE fused bt-GEMM, bf16 MFMA, fp32 acc)
//   RoPE(q,k) ; flash attention ; out = attn@Wo^T (fp32 store)
//
// R9: attention staging rewritten.
//  (a) K/V tiles staged via global_load_lds (16B) with both-sides XOR chunk
//      swizzle (K [64][128] linear, chunk^=row&15; V [128][64], chunk^=row&7)
//      -> conflict-free ds_read_b128, no VGPR roundtrip, no staging VALU.
//  (b) issue-early pipeline, counted vmcnt, raw s_barrier: stage V(t)+K(t+1)
//      at iter top; QK+softmax from K[cur]; vmcnt(4)+bar (V ready, K(t+1)
//      still in flight); PV; vmcnt(0)+bar. Load latency hides under compute.
//  (c) XCD-aware decode: xcd == hkv, so each XCD's L2 caches exactly its own
//      2MB K/V stream (longest-q-tiles-first preserved within XCD).
//  (d) rope+transpose merged into one dispatch (6 -> 5 kernels).
// GEMM unchanged (m97-structure ceiling, MfmaUtil 41%, 0 conflicts).
// ---------------------------------------------------------------------------

typedef __bf16 bf16x8 __attribute__((ext_vector_type(8)));
typedef __bf16 bf16x4 __attribute__((ext_vector_type(4)));
typedef float  f32x4  __attribute__((ext_vector_type(4)));

#define B_   2
#define S_   2048
#define DM_  4096
#define H_   32
#define HKV_ 8
#define D_   128
#define QS_  6144   // fused QKV row stride (4096 Q | 1024 K | 1024 V)

static __device__ __forceinline__ f32x4 mfma16(bf16x8 a, bf16x8 b, f32x4 c) {
    return __builtin_amdgcn_mfma_f32_16x16x32_bf16(a, b, c, 0, 0, 0);
}

// async global -> LDS, 16 bytes per lane. LDS dest must be wave-uniform base;
// HW writes lane i at base + i*16.
static __device__ __forceinline__ void gload_lds16(const __bf16* g, __bf16* l) {
    __builtin_amdgcn_global_load_lds(
        (const __attribute__((address_space(1))) void*)g,
        (__attribute__((address_space(3))) void*)l, 16, 0, 0);
}

static __device__ __forceinline__ void waitv0() { asm volatile("s_waitcnt vmcnt(0)" ::: "memory"); }
static __device__ __forceinline__ void waitv4() { asm volatile("s_waitcnt vmcnt(4)" ::: "memory"); }

// ---------------------------------------------------------------------------
// fused fp32 -> bf16 over 5 tensors (RNE via cast), 4 elems/thread.
// ---------------------------------------------------------------------------
__global__ void f32_to_bf16_all(const float* __restrict__ X,
                                const float* __restrict__ Wq,
                                const float* __restrict__ Wk,
                                const float* __restrict__ Wv,
                                const float* __restrict__ Wo,
                                __bf16* __restrict__ Xb,
                                __bf16* __restrict__ Wqkv,
                                __bf16* __restrict__ Wob,
                                int nX, int nQ, int nK) {
    int idx = (blockIdx.x * blockDim.x + threadIdx.x) * 4;
    const float* src;
    __bf16* dst;
    int o0 = nX, o1 = nX + nQ, o2 = o1 + nK, o3 = o2 + nK;
    if (idx < o0)      { src = X  + idx;        dst = Xb   + idx; }
    else if (idx < o1) { src = Wq + (idx - o0); dst = Wqkv + (idx - o0); }
    else if (idx < o2) { src = Wk + (idx - o1); dst = Wqkv + nQ + (idx - o1); }
    else if (idx < o3) { src = Wv + (idx - o2); dst = Wqkv + nQ + nK + (idx - o2); }
    else               { src = Wo + (idx - o3); dst = Wob  + (idx - o3); }
    float4 v = *(const float4*)src;
    bf16x4 o;
    o[0] = (__bf16)v.x; o[1] = (__bf16)v.y; o[2] = (__bf16)v.z; o[3] = (__bf16)v.w;
    *(bf16x4*)dst = o;
}

// ---------------------------------------------------------------------------
// bt-GEMM: C[m,n] = sum_k A[m,k]*B[n,k]. bf16 in, fp32 acc, OutT out.
// 128x128 tile, BK=64, 4 waves -> 64x64 each, 4x4 MFMA acc.
// Async global_load_lds staging, both-sides XOR swizzle (rule #21),
// bijective XCD block swizzle (grids % 8 == 0).  [unchanged since R7]
// ---------------------------------------------------------------------------
#define BK_ 64

template <typename OutT>
__global__ __launch_bounds__(256) void gemm_bt(const __bf16* __restrict__ A,
                                               const __bf16* __restrict__ Bm,
                                               OutT* __restrict__ C,
                                               int M, int N, int K) {
    __shared__ __align__(16) __bf16 As[128 * BK_];
    __shared__ __align__(16) __bf16 Bs[128 * BK_];
    const int tid  = threadIdx.x;
    const int lane = tid & 63;
    const int wave = tid >> 6;
    const int wm   = (wave >> 1) * 64;
    const int wn   = (wave & 1) * 64;
    const int m15  = lane & 15;
    const int q4   = lane >> 4;
    const int r8   = lane >> 3;                    // = row & 7 for staging
    const int csw  = ((lane & 7) ^ r8) * 8;        // swizzled global col (elems)
    const int xr   = (m15 & 7) * 8;                // read-side XOR (elems)

    const int nblk = gridDim.x * gridDim.y;
    const int lid  = blockIdx.x + blockIdx.y * gridDim.x;
    const int swzb = (lid & 7) * (nblk >> 3) + (lid >> 3);
    const int bx   = swzb % gridDim.x;
    const int by   = swzb / gridDim.x;

    const __bf16* Ab = A  + (size_t)(bx * 128) * K;
    const __bf16* Bb = Bm + (size_t)(by * 128) * K;

    f32x4 acc[4][4];
#pragma unroll
    for (int i = 0; i < 4; ++i)
#pragma unroll
        for (int j = 0; j < 4; ++j) acc[i][j] = (f32x4){0.f, 0.f, 0.f, 0.f};

    for (int k0 = 0; k0 < K; k0 += BK_) {
        __syncthreads();
#pragma unroll
        for (int it = 0; it < 4; ++it) {
            const int e   = it * 2048 + wave * 512;
            const int row = it * 32 + wave * 8 + r8;
            const size_t goff = (size_t)row * K + k0 + csw;
            gload_lds16(Ab + goff, As + e);
            gload_lds16(Bb + goff, Bs + e);
        }
        __syncthreads();
#pragma unroll
        for (int kk = 0; kk < 2; ++kk) {
            bf16x8 af[4], bfr[4];
            const int rc = ((kk * 4 + q4) * 8) ^ xr;
#pragma unroll
            for (int i = 0; i < 4; ++i)
                af[i] = *(const bf16x8*)&As[(wm + i * 16 + m15) * BK_ + rc];
#pragma unroll
            for (int j = 0; j < 4; ++j)
                bfr[j] = *(const bf16x8*)&Bs[(wn + j * 16 + m15) * BK_ + rc];
#pragma unroll
            for (int i = 0; i < 4; ++i)
#pragma unroll
                for (int j = 0; j < 4; ++j)
                    acc[i][j] = mfma16(af[i], bfr[j], acc[i][j]);
        }
    }
#pragma unroll
    for (int i = 0; i < 4; ++i)
#pragma unroll
        for (int j = 0; j < 4; ++j) {
            int row = bx * 128 + wm + i * 16 + q4 * 4;
            int col = by * 128 + wn + j * 16 + m15;
#pragma unroll
            for (int r = 0; r < 4; ++r)
                C[(size_t)(row + r) * N + col] = (OutT)acc[i][j][r];
        }
}

// ---------------------------------------------------------------------------
// RoPE (heads 0..39 = Q|K of the fused QKV rows) + V transpose, ONE dispatch.
// Blocks [0, RB): rope. Blocks [RB, RB+TB): transpose V -> Vt [B,HKV,128,S].
// ---------------------------------------------------------------------------
#define RB_ 40960   // (B*S)*(H+HKV)*64 / 256
#define TB_ 16384   // B*HKV*D*S / 256

__global__ void rope_transpose(__bf16* __restrict__ QKV, const int* __restrict__ pos,
                               __bf16* __restrict__ Vt) {
    int bid = blockIdx.x;
    if (bid < RB_) {
        int idx = bid * 256 + threadIdx.x;
        int i  = idx & 63;
        int t  = idx >> 6;
        int h  = t % (H_ + HKV_);
        int bs = t / (H_ + HKV_);
        float p   = (float)pos[bs];
        float inv = exp2f(-(float)i * 0.20762050593046326f);
        float ang = p * inv;
        float s, c;
        sincosf(ang, &s, &c);
        __bf16* base = QKV + (size_t)bs * QS_ + h * 128 + i;
        float x1 = (float)base[0];
        float x2 = (float)base[64];
        base[0]  = (__bf16)(x1 * c - x2 * s);
        base[64] = (__bf16)(x2 * c + x1 * s);
    } else {
        int idx = (bid - RB_) * 256 + threadIdx.x;
        int s  = idx & (S_ - 1);
        int d  = (idx >> 11) & (D_ - 1);
        int hb = idx >> 18;
        int b  = hb >> 3;
        int h  = hb & 7;
        Vt[idx] = QKV[((size_t)(b * S_ + s)) * QS_ + (H_ + HKV_) * D_ + h * D_ + d];
    }
}

// ---------------------------------------------------------------------------
// Block-level flash attention, causal, GQA rep=4, no-max softmax (exact).
// Block = 4 waves = one (b,h,128-row Q tile); wave owns 32 rows (2 rgroups).
// K double-buffered + V single-buffered LDS via global_load_lds with XOR
// chunk swizzle; issue-early staging, counted vmcnt, raw barriers.
// Decode: xcd (= blockIdx&7) == hkv for per-XCD K/V L2 residency.
// ---------------------------------------------------------------------------
#define PSW 72

__global__ __launch_bounds__(256, 2) void attn_kernel(const __bf16* __restrict__ Q,
                                                      const __bf16* __restrict__ Kc,
                                                      const __bf16* __restrict__ Vt,
                                                      __bf16* __restrict__ O) {
    __shared__ __align__(16) __bf16 Ks[2][64 * 128];
    __shared__ __align__(16) __bf16 Vs[128 * 64];
    __shared__ __align__(16) __bf16 Ps[4][32 * PSW];

    const int tid  = threadIdx.x;
    const int wave = tid >> 6;
    const int lane = tid & 63;
    const int m15  = lane & 15;
    const int q4   = lane >> 4;

    // XCD-grouped decode: hkv == xcd; within xcd: h fastest, then b, then qt
    const int gg  = blockIdx.x;
    const int hkv = gg & 7;
    const int ii  = gg >> 3;                  // 0..127
    const int h   = hkv * 4 + (ii & 3);
    const int b   = (ii >> 2) & 1;
    const int qt  = 15 - (ii >> 3);           // longest tiles first
    const int qbase = qt * 128 + wave * 32;

    // staging lane constants (both-sides XOR swizzle)
    const int krow = tid >> 4;                       // 0..15 (row & 15)
    const int kcol = ((tid & 15) ^ krow) * 8;        // swizzled global col (elems)
    const int vrow = tid >> 3;                       // 0..31
    const int vcol = ((tid & 7) ^ (vrow & 7)) * 8;
    const int lbase = wave * 512;                    // wave-uniform LDS chunk base

    // Q fragments: 2 row-groups x 4 k-chunks (A-operand layout)
    bf16x8 qf[2][4];
#pragma unroll
    for (int rg = 0; rg < 2; ++rg) {
        const __bf16* qrow = Q + ((size_t)(b * S_ + qbase + rg * 16 + m15)) * QS_ + h * D_;
#pragma unroll
        for (int kk = 0; kk < 4; ++kk) qf[rg][kk] = *(const bf16x8*)(qrow + kk * 32 + q4 * 8);
    }

    f32x4 o[2][8];
#pragma unroll
    for (int rg = 0; rg < 2; ++rg)
#pragma unroll
        for (int t = 0; t < 8; ++t) o[rg][t] = (f32x4){0.f, 0.f, 0.f, 0.f};
    float li[2][4];
#pragma unroll
    for (int rg = 0; rg < 2; ++rg)
#pragma unroll
        for (int r = 0; r < 4; ++r) li[rg][r] = 0.f;

    const __bf16* Kg = Kc + (size_t)(b * S_) * QS_ + hkv * D_;
    const __bf16* Vg = Vt + (size_t)((b * HKV_ + hkv) * D_) * S_;
    const float scale = 0.08838834764831845f; // 1/sqrt(128)
    __bf16* pl = &Ps[wave][0];

    const int nt = 2 * qt + 2;
    // prologue: stage K tile 0 into Ks[0]
#pragma unroll
    for (int r = 0; r < 4; ++r)
        gload_lds16(Kg + (size_t)(r * 16 + krow) * QS_ + kcol, &Ks[0][r * 2048 + lbase]);
    waitv0();
    __builtin_amdgcn_s_barrier();

    for (int t = 0; t < nt; ++t) {
        const int kb  = t * 64;
        const int cur = t & 1;
        // ---- issue-early stages: V(t) first (drained at mid), K(t+1) second
#pragma unroll
        for (int r = 0; r < 4; ++r)
            gload_lds16(Vg + (size_t)(r * 32 + vrow) * S_ + kb + vcol, &Vs[r * 2048 + lbase]);
        const bool haveK = (t + 1 < nt);
        if (haveK) {
#pragma unroll
            for (int r = 0; r < 4; ++r)
                gload_lds16(Kg + (size_t)(kb + 64 + r * 16 + krow) * QS_ + kcol,
                            &Ks[cur ^ 1][r * 2048 + lbase]);
        }
        const bool compute = (kb <= qbase + 31);   // wave-uniform causal skip
        bf16x8 pf[2][2];
        if (compute) {
            // ---- QK^T from Ks[cur] (swizzled chunk reads)
            f32x4 sg[2][4];
            __builtin_amdgcn_s_setprio(1);
#pragma unroll
            for (int g = 0; g < 4; ++g) {
                bf16x8 kf[4];
#pragma unroll
                for (int kk = 0; kk < 4; ++kk)
                    kf[kk] = *(const bf16x8*)&Ks[cur][(g * 16 + m15) * 128 + (((kk * 4 + q4) ^ m15) * 8)];
                sg[0][g] = (f32x4){0.f, 0.f, 0.f, 0.f};
                sg[1][g] = (f32x4){0.f, 0.f, 0.f, 0.f};
#pragma unroll
                for (int kk = 0; kk < 4; ++kk) {
                    sg[0][g] = mfma16(qf[0][kk], kf[kk], sg[0][g]);
                    sg[1][g] = mfma16(qf[1][kk], kf[kk], sg[1][g]);
                }
            }
            __builtin_amdgcn_s_setprio(0);
            const bool masked = (kb + 63 > qbase);
            // ---- no-max softmax (exact: shift-invariant, scores bounded)
#pragma unroll
            for (int rg = 0; rg < 2; ++rg) {
                float p[4][4];
#pragma unroll
                for (int r = 0; r < 4; ++r) {
                    int row = qbase + rg * 16 + q4 * 4 + r;
#pragma unroll
                    for (int g = 0; g < 4; ++g) {
                        bool dead = masked && (kb + g * 16 + m15 > row);
                        p[g][r] = dead ? 0.f : __expf(sg[rg][g][r] * scale);
                    }
                    li[rg][r] += (p[0][r] + p[1][r]) + (p[2][r] + p[3][r]);
                }
#pragma unroll
                for (int g = 0; g < 4; ++g)
#pragma unroll
                    for (int r = 0; r < 4; ++r)
                        pl[(rg * 16 + q4 * 4 + r) * PSW + g * 16 + m15] = (__bf16)p[g][r];
            }
            // ---- P A-fragments (wave-private LDS roundtrip)
#pragma unroll
            for (int rg = 0; rg < 2; ++rg)
#pragma unroll
                for (int kg = 0; kg < 2; ++kg)
                    pf[rg][kg] = *(const bf16x8*)(pl + (rg * 16 + m15) * PSW + kg * 32 + q4 * 8);
        }
        // ---- V(t) landed (oldest 4), K(t+1) may stay in flight
        if (haveK) waitv4(); else waitv0();
        __builtin_amdgcn_s_barrier();
        if (compute) {
            __builtin_amdgcn_s_setprio(1);
#pragma unroll
            for (int t8 = 0; t8 < 8; ++t8) {
#pragma unroll
                for (int kg = 0; kg < 2; ++kg) {
                    bf16x8 vf = *(const bf16x8*)&Vs[(t8 * 16 + m15) * 64 + (((kg * 4 + q4) ^ (m15 & 7)) * 8)];
                    o[0][t8] = mfma16(pf[0][kg], vf, o[0][t8]);
                    o[1][t8] = mfma16(pf[1][kg], vf, o[1][t8]);
                }
            }
            __builtin_amdgcn_s_setprio(0);
        }
        // ---- K(t+1) landed; all reads of Ks[cur]/Vs retired
        waitv0();
        __builtin_amdgcn_s_barrier();
    }
    // ---- epilogue: reduce li across the 16 m15 lanes (once), then scale
#pragma unroll
    for (int rg = 0; rg < 2; ++rg)
#pragma unroll
        for (int r = 0; r < 4; ++r) {
#pragma unroll
            for (int off = 1; off < 16; off <<= 1)
                li[rg][r] += __shfl_xor(li[rg][r], off);
        }
#pragma unroll
    for (int rg = 0; rg < 2; ++rg) {
        __bf16* ob = O + ((size_t)(b * S_ + qbase + rg * 16 + q4 * 4)) * (H_ * D_) + h * D_;
#pragma unroll
        for (int t = 0; t < 8; ++t)
#pragma unroll
            for (int r = 0; r < 4; ++r)
                ob[(size_t)r * (H_ * D_) + t * 16 + m15] = (__bf16)(o[rg][t][r] / li[rg][r]);
    }
}

// ---------------------------------------------------------------------------
extern "C" void kernel_launch(void* const* d_in, const int* in_sizes, int n_in,
                              void* d_out, int out_size, void* d_ws, size_t ws_size,
                              hipStream_t stream) {
    const float* X   = (const float*)d_in[0];
    const int*   pos = (const int*)d_in[1];
    const float* Wq  = (const float*)d_in[2];
    const float* Wk  = (const float*)d_in[3];
    const float* Wv  = (const float*)d_in[4];
    const float* Wo  = (const float*)d_in[5];
    float*       out = (float*)d_out;

    char* ws = (char*)d_ws;
    __bf16* Xb   = (__bf16*)(ws);                 // [4096][4096]
    __bf16* Wqkv = (__bf16*)(ws + 33554432);      // [6144][4096]  (Wq|Wk|Wv rows)
    __bf16* Wob  = (__bf16*)(ws + 83886080);      // [4096][4096]
    __bf16* QKV  = (__bf16*)(ws + 117440512);     // [4096][6144]  (Q|K|V cols)
    __bf16* Vtp  = Wqkv;  // alias (weights dead after fused QKV gemm)
    __bf16* Attn = Xb;    // alias (Xb dead after fused QKV gemm)

    const int M  = B_ * S_;
    const int nX = M * DM_;
    const int nQ = H_ * D_ * DM_;
    const int nK = HKV_ * D_ * DM_;

    {
        int ntot = nX + 2 * nQ + 2 * nK;
        f32_to_bf16_all<<<(ntot / 4 + 255) / 256, 256, 0, stream>>>(
            X, Wq, Wk, Wv, Wo, Xb, Wqkv, Wob, nX, nQ, nK);
    }

    // fused QKV projection: [4096][6144] = Xb @ Wqkv^T   (grid 32x48 = 6/CU)
    gemm_bt<__bf16><<<dim3(M / 128, QS_ / 128), 256, 0, stream>>>(Xb, Wqkv, QKV, M, QS_, DM_);

    // RoPE (Q|K heads) + V transpose in one dispatch
    rope_transpose<<<RB_ + TB_, 256, 0, stream>>>(QKV, pos, Vtp);

    // attention: 1024 blocks, xcd==hkv grouping
    attn_kernel<<<B_ * H_ * (S_ / 128), 256, 0, stream>>>(QKV, QKV + H_ * D_, Vtp, Attn);

    gemm_bt<float><<<dim3(M / 128, (H_ * D_) / 128), 256, 0, stream>>>(Attn, Wob, out, M, H_ * D_, DM_);
}